// Round 2
// baseline (1405.151 us; speedup 1.0000x reference)
//
#include <hip/hip_runtime.h>
#include <hip/hip_bf16.h>
#include <cstdint>
#include <cmath>

// ---------------------------------------------------------------------------
// TransLayer block: QKV proj -> softmax(QK^T/sqrt(D)) V -> GELU FFN -> resid.
// B=8, N=2048, D=1028 (K-pad 1056, N-pad 1152), H=4112 (pad 4224).
// All GEMMs: C = A @ B^T, A[M,K], B[Nc,K], K-contiguous bf16, fp32 acc.
// Workspace-adaptive: attention in groups of G batches, FFN in R-row chunks.
// ---------------------------------------------------------------------------

typedef __bf16 bf16;
typedef __bf16 bf16x4 __attribute__((ext_vector_type(4)));
typedef __bf16 bf16x8 __attribute__((ext_vector_type(8)));
typedef float  f32x4  __attribute__((ext_vector_type(4)));

#define D_REAL   1028
#define D_PADK   1056   // K-dim pad (mult of 32)
#define D_PADN   1152   // N-dim pad (mult of 128)
#define H_REAL   4112
#define H_PAD    4224
#define NTOK     2048
#define NB       8
#define MTOT     (NB*NTOK)           // 16384
#define SLAB_X   ((size_t)NTOK*D_PADK)   // 2,162,688 elems
#define SLAB_S   ((size_t)NTOK*NTOK)     // 4,194,304 elems
#define WSLAB    ((size_t)D_PADN*D_PADK)

// async 16B/lane global->LDS; LDS dest wave-uniform base, HW scatters lane*16.
__device__ __forceinline__ void async16(const void* g, void* l) {
    __builtin_amdgcn_global_load_lds(
        (__attribute__((address_space(1))) void*)(uintptr_t)g,
        (__attribute__((address_space(3))) void*)(uint32_t)(uintptr_t)l,
        16, 0, 0);
}

// EPI: 0 = bf16 out (+bias), 1 = bf16 transposed out for V^T (+bias),
//      2 = fp32 out * scale, 3 = gelu(acc+bias) -> bf16, 4 = fp32 acc+bias+resid
template <int EPI>
__global__ __launch_bounds__(256)
void gemm_bt(const bf16* __restrict__ A, size_t strideA,
             const bf16* __restrict__ B, size_t strideB,
             const float* __restrict__ bias, size_t strideBias,
             void* __restrict__ Out, size_t strideOut,
             int K, int outPitch, int colBound, float scale,
             const float* __restrict__ resid)
{
    __shared__ __attribute__((aligned(16))) bf16 tA[128 * 32];
    __shared__ __attribute__((aligned(16))) bf16 tB[128 * 32];

    const int z = blockIdx.z;
    A += (size_t)z * strideA;
    B += (size_t)z * strideB;
    if (bias) bias += (size_t)z * strideBias;

    const int tid  = threadIdx.x;
    const int lane = tid & 63;
    const int wv   = tid >> 6;        // wave 0..3
    const int wm   = wv >> 1;         // 2x2 wave grid, 64x64 each
    const int wn   = wv & 1;

    f32x4 acc[4][4] = {};

    const int stgRow = lane >> 2;
    const int stgCol = (lane & 3) * 8;     // elements
    const bf16* gA = A + (size_t)(blockIdx.y * 128 + wv * 32 + stgRow) * K + stgCol;
    const bf16* gB = B + (size_t)(blockIdx.x * 128 + wv * 32 + stgRow) * K + stgCol;
    bf16* lA = &tA[(wv * 32) * 32];
    bf16* lB = &tB[(wv * 32) * 32];

    const int lr = lane & 15;
    const int lq = lane >> 4;

    for (int k0 = 0; k0 < K; k0 += 32) {
        async16(gA,                  lA);
        async16(gA + (size_t)16 * K, lA + 16 * 32);
        async16(gB,                  lB);
        async16(gB + (size_t)16 * K, lB + 16 * 32);
        gA += 32; gB += 32;
        __syncthreads();

        bf16x8 af[4], bfr[4];
        #pragma unroll
        for (int i = 0; i < 4; ++i) {
            af[i]  = *(const bf16x8*)&tA[(wm * 64 + i * 16 + lr) * 32 + lq * 8];
            bfr[i] = *(const bf16x8*)&tB[(wn * 64 + i * 16 + lr) * 32 + lq * 8];
        }
        #pragma unroll
        for (int i = 0; i < 4; ++i)
            #pragma unroll
            for (int j = 0; j < 4; ++j)
                acc[i][j] = __builtin_amdgcn_mfma_f32_16x16x32_bf16(
                    af[i], bfr[j], acc[i][j], 0, 0, 0);
        __syncthreads();
    }

    // C/D layout: col = lane&15, row = (lane>>4)*4 + reg  [m89/m91]
    const int bx = blockIdx.x, by = blockIdx.y;
    #pragma unroll
    for (int i = 0; i < 4; ++i) {
        #pragma unroll
        for (int j = 0; j < 4; ++j) {
            f32x4 v = acc[i][j];
            const int cg = bx * 128 + wn * 64 + j * 16 + lr;
            if (cg >= colBound) continue;
            const int rowBase = by * 128 + wm * 64 + i * 16 + lq * 4;
            const float bs = bias ? bias[cg] : 0.0f;
            #pragma unroll
            for (int r = 0; r < 4; ++r) {
                const int mg = rowBase + r;
                const float val = v[r];
                if (EPI == 0) {
                    ((bf16*)Out + (size_t)z * strideOut)[(size_t)mg * outPitch + cg] =
                        (bf16)(val + bs);
                } else if (EPI == 1) {
                    const int bb = mg >> 11, t = mg & (NTOK - 1);
                    ((bf16*)Out)[((size_t)bb * D_PADN + cg) * NTOK + t] = (bf16)(val + bs);
                } else if (EPI == 2) {
                    ((float*)Out + (size_t)z * strideOut)[(size_t)mg * outPitch + cg] =
                        val * scale;
                } else if (EPI == 3) {
                    const float u = val + bs;
                    const float g = 0.5f * u * (1.0f + erff(u * 0.70710678118654752f));
                    ((bf16*)Out)[(size_t)mg * outPitch + cg] = (bf16)g;
                } else {
                    ((float*)Out)[(size_t)mg * outPitch + cg] =
                        val + bs + resid[(size_t)mg * outPitch + cg];
                }
            }
        }
    }
}

// fp32 [R,C] -> zero-padded bf16 [gridDim.y, CP]
__global__ __launch_bounds__(256)
void cvt_pad(const float* __restrict__ src, int R, int C,
             bf16* __restrict__ dst, int CP)
{
    const int c = blockIdx.x * 256 + threadIdx.x;
    const int r = blockIdx.y;
    if (c >= CP) return;
    const float v = (r < R && c < C) ? src[(size_t)r * C + c] : 0.0f;
    dst[(size_t)r * CP + c] = (bf16)v;
}

__global__ __launch_bounds__(256)
void pad_bias(const float* __restrict__ src, int n, float* __restrict__ dst, int np)
{
    const int i = blockIdx.x * 256 + threadIdx.x;
    if (i < np) dst[i] = (i < n) ? src[i] : 0.0f;
}

// row softmax over 2048 fp32 logits -> bf16 weights; one wave per row
__global__ __launch_bounds__(256)
void softmax_bf16(const float* __restrict__ S, bf16* __restrict__ W)
{
    const int row  = blockIdx.x * 4 + (threadIdx.x >> 6);
    const int lane = threadIdx.x & 63;
    const float* s = S + (size_t)row * NTOK + lane * 4;

    float4 v[8];
    #pragma unroll
    for (int j = 0; j < 8; ++j) v[j] = *(const float4*)(s + j * 256);

    float m = -1e30f;
    #pragma unroll
    for (int j = 0; j < 8; ++j)
        m = fmaxf(m, fmaxf(fmaxf(v[j].x, v[j].y), fmaxf(v[j].z, v[j].w)));
    #pragma unroll
    for (int off = 32; off > 0; off >>= 1) m = fmaxf(m, __shfl_xor(m, off, 64));

    float sum = 0.0f;
    #pragma unroll
    for (int j = 0; j < 8; ++j) {
        v[j].x = __expf(v[j].x - m); v[j].y = __expf(v[j].y - m);
        v[j].z = __expf(v[j].z - m); v[j].w = __expf(v[j].w - m);
        sum += v[j].x + v[j].y + v[j].z + v[j].w;
    }
    #pragma unroll
    for (int off = 32; off > 0; off >>= 1) sum += __shfl_xor(sum, off, 64);
    const float inv = 1.0f / sum;

    bf16* o = W + (size_t)row * NTOK + lane * 4;
    #pragma unroll
    for (int j = 0; j < 8; ++j) {
        bf16x4 t = { (bf16)(v[j].x * inv), (bf16)(v[j].y * inv),
                     (bf16)(v[j].z * inv), (bf16)(v[j].w * inv) };
        *(bf16x4*)(o + j * 256) = t;
    }
}

// ---------------------------------------------------------------------------
// fixed workspace region (bytes):
//   WQKV 0..7,299,072  WE ..16,220,160  WO ..25,952,256  BQKV ..25,966,080
//   BE ..25,982,976  XBF(34,603,008; attn overwrites in place) ..60,585,984
//   VT(37,748,736) ..98,334,720 = OFF_SCR.  Scratch region is adaptive.
// ---------------------------------------------------------------------------
#define OFF_WQKV   0u
#define OFF_WE     7299072u
#define OFF_WO     16220160u
#define OFF_BQKV   25952256u
#define OFF_BE     25966080u
#define OFF_XBF    25982976u
#define OFF_VT     60585984u
#define OFF_SCR    98334720u

extern "C" void kernel_launch(void* const* d_in, const int* in_sizes, int n_in,
                              void* d_out, int out_size, void* d_ws, size_t ws_size,
                              hipStream_t stream)
{
    const float* x  = (const float*)d_in[0];
    const float* Wq = (const float*)d_in[1];
    const float* bq = (const float*)d_in[2];
    const float* Wk = (const float*)d_in[3];
    const float* bk = (const float*)d_in[4];
    const float* Wv = (const float*)d_in[5];
    const float* bv = (const float*)d_in[6];
    const float* We = (const float*)d_in[7];
    const float* be = (const float*)d_in[8];
    const float* Wo = (const float*)d_in[9];
    const float* bo = (const float*)d_in[10];

    char* ws = (char*)d_ws;
    bf16*  Wqkv = (bf16*)(ws + OFF_WQKV);
    bf16*  WeP  = (bf16*)(ws + OFF_WE);
    bf16*  WoP  = (bf16*)(ws + OFF_WO);
    float* Bqkv = (float*)(ws + OFF_BQKV);
    float* BeP  = (float*)(ws + OFF_BE);
    bf16*  Xbf  = (bf16*)(ws + OFF_XBF);   // x bf16; attn overwrites per group
    bf16*  Vt   = (bf16*)(ws + OFF_VT);
    char*  scr  = ws + OFF_SCR;

    // adaptive scratch: G batches of attention per iteration, R-row FFN chunks
    const size_t avail = ws_size > OFF_SCR ? ws_size - OFF_SCR : 0;
    int G, R;
    if      (avail >= 270532608u) { G = 8; R = 16384; }  // 8*(QK+S+Wsm)
    else if (avail >= 135266304u) { G = 4; R = 8192;  }
    else if (avail >=  67633152u) { G = 2; R = 4096;  }
    else                          { G = 1; R = 4096;  }  // needs 34,603,008

    bf16*  Qs  = (bf16*)scr;                                    // G*2 slabs Q,K
    float* Ss  = (float*)(scr + (size_t)G * 8650752u);          // G fp32 score slabs
    bf16*  Wsm = (bf16*)(scr + (size_t)G * 8650752u + (size_t)G * 16777216u);
    bf16*  Hb  = (bf16*)scr;                                    // FFN phase (aliases)

    const dim3 blk(256);
    const float inv_sqrt_d = (float)(1.0 / sqrt((double)D_REAL));

    // ---- convert + pad to bf16 ----
    cvt_pad<<<dim3(5, MTOT), blk, 0, stream>>>(x, MTOT, D_REAL, Xbf, D_PADK);
    cvt_pad<<<dim3(5, D_PADN), blk, 0, stream>>>(Wq, D_REAL, D_REAL, Wqkv, D_PADK);
    cvt_pad<<<dim3(5, D_PADN), blk, 0, stream>>>(Wk, D_REAL, D_REAL, Wqkv + WSLAB, D_PADK);
    cvt_pad<<<dim3(5, D_PADN), blk, 0, stream>>>(Wv, D_REAL, D_REAL, Wqkv + 2 * WSLAB, D_PADK);
    cvt_pad<<<dim3(5, H_PAD), blk, 0, stream>>>(We, H_REAL, D_REAL, WeP, D_PADK);
    cvt_pad<<<dim3(17, D_PADN), blk, 0, stream>>>(Wo, D_REAL, H_REAL, WoP, H_PAD);
    pad_bias<<<dim3(5), blk, 0, stream>>>(bq, D_REAL, Bqkv, D_PADN);
    pad_bias<<<dim3(5), blk, 0, stream>>>(bk, D_REAL, Bqkv + D_PADN, D_PADN);
    pad_bias<<<dim3(5), blk, 0, stream>>>(bv, D_REAL, Bqkv + 2 * D_PADN, D_PADN);
    pad_bias<<<dim3(17), blk, 0, stream>>>(be, H_REAL, BeP, H_PAD);

    // ---- V projection (all batches), stored transposed: Vt[b][d][t] ----
    gemm_bt<1><<<dim3(9, 128, 1), blk, 0, stream>>>(
        Xbf, 0, Wqkv + 2 * WSLAB, 0, Bqkv + 2 * D_PADN, 0,
        Vt, 0, D_PADK, NTOK, D_PADN, 1.0f, nullptr);

    // ---- attention, G batches per iteration ----
    for (int g0 = 0; g0 < NB; g0 += G) {
        // Q proj for batches [g0, g0+G)
        gemm_bt<0><<<dim3(9, 16, G), blk, 0, stream>>>(
            Xbf + (size_t)g0 * SLAB_X, SLAB_X, Wqkv, 0, Bqkv, 0,
            Qs, 2 * SLAB_X, D_PADK, D_PADK, D_PADK, 1.0f, nullptr);
        // K proj
        gemm_bt<0><<<dim3(9, 16, G), blk, 0, stream>>>(
            Xbf + (size_t)g0 * SLAB_X, SLAB_X, Wqkv + WSLAB, 0, Bqkv + D_PADN, 0,
            Qs + SLAB_X, 2 * SLAB_X, D_PADK, D_PADK, D_PADK, 1.0f, nullptr);
        // scores = (Q @ K^T) * inv_sqrt_d  (fp32)
        gemm_bt<2><<<dim3(16, 16, G), blk, 0, stream>>>(
            Qs, 2 * SLAB_X, Qs + SLAB_X, 2 * SLAB_X, nullptr, 0,
            Ss, SLAB_S, D_PADK, NTOK, NTOK, inv_sqrt_d, nullptr);
        // softmax rows -> bf16 weights
        softmax_bf16<<<dim3(G * 512), blk, 0, stream>>>(Ss, Wsm);
        // attn = W @ Vt^T, overwrite Xbf slab (x no longer needed there)
        gemm_bt<0><<<dim3(9, 16, G), blk, 0, stream>>>(
            Wsm, SLAB_S, Vt + (size_t)g0 * D_PADN * NTOK, (size_t)D_PADN * NTOK,
            nullptr, 0, Xbf + (size_t)g0 * SLAB_X, SLAB_X,
            NTOK, D_PADK, D_PADK, 1.0f, nullptr);
    }

    // ---- FFN in R-row chunks: h = gelu(attn@We^T+be); out = h@Wo^T+bo+x ----
    for (int r0 = 0; r0 < MTOT; r0 += R) {
        gemm_bt<3><<<dim3(33, R / 128, 1), blk, 0, stream>>>(
            Xbf + (size_t)r0 * D_PADK, 0, WeP, 0, BeP, 0,
            Hb, 0, D_PADK, H_PAD, H_PAD, 1.0f, nullptr);
        gemm_bt<4><<<dim3(9, R / 128, 1), blk, 0, stream>>>(
            Hb, 0, WoP, 0, bo, 0,
            (float*)d_out + (size_t)r0 * D_REAL, 0, H_PAD, D_REAL, D_REAL, 1.0f,
            x + (size_t)r0 * D_REAL);
    }
}

// Round 3
// 1200.941 us; speedup vs baseline: 1.1700x; 1.1700x over previous
//
#include <hip/hip_runtime.h>
#include <hip/hip_bf16.h>
#include <cstdint>
#include <cmath>

// ---------------------------------------------------------------------------
// TransLayer block: fused QKV proj -> softmax(QK^T/sqrt(D)) V -> GELU FFN.
// B=8, N=2048, D=1028 (K-pad 1056, N-pad 1152), H=4112 (pad 4224).
// GEMMs: C = A @ B^T, K-contiguous bf16, fp32 acc, 128x128 tiles, MFMA 16x16x32.
// LDS XOR-swizzled (kills the 8-way ds_read_b128 bank conflict).
// Batched GEMMs (S, PV) XCD-pinned: batch = blockIdx.x (fastest) so each XCD
// keeps one batch's B-slab in its L2.
// ---------------------------------------------------------------------------

typedef __bf16 bf16;
typedef __bf16 bf16x8 __attribute__((ext_vector_type(8)));
typedef float  f32x4  __attribute__((ext_vector_type(4)));

#define D_REAL   1028
#define D_PADK   1056
#define D_PADN   1152
#define H_REAL   4112
#define H_PAD    4224
#define NTOK     2048
#define NB       8
#define MTOT     (NB*NTOK)               // 16384
#define SLAB_X   ((size_t)NTOK*D_PADK)   // 2,162,688 elems
#define SLAB_S   ((size_t)NTOK*NTOK)     // 4,194,304 elems
#define WSLAB    ((size_t)D_PADN*D_PADK)
#define VSLAB    ((size_t)D_PADN*NTOK)

__device__ __forceinline__ void async16(const void* g, void* l) {
    __builtin_amdgcn_global_load_lds(
        (__attribute__((address_space(1))) void*)(uintptr_t)g,
        (__attribute__((address_space(3))) void*)(uint32_t)(uintptr_t)l,
        16, 0, 0);
}

// EPI: 0 = bf16 out (+bias), 3 = gelu(acc+bias)->bf16, 4 = fp32 acc+bias+resid,
//      5 = fused QKV (Q/K to slabs, V transposed to OutV), 6 = bf16 out*scale
template <int EPI, bool XPIN>
__global__ __launch_bounds__(256)
void gemm_bt(const bf16* __restrict__ A, size_t strideA,
             const bf16* __restrict__ B, size_t strideB,
             const float* __restrict__ bias, size_t strideBias,
             void* __restrict__ Out, size_t strideOut,
             bf16* __restrict__ OutV,
             int K, int outPitch, int colBound, float scale,
             const float* __restrict__ resid)
{
    __shared__ __attribute__((aligned(16))) bf16 tA[128 * 32];
    __shared__ __attribute__((aligned(16))) bf16 tB[128 * 32];

    int bx, by, bz;
    if (XPIN) { bz = blockIdx.x; by = blockIdx.y; bx = blockIdx.z; }
    else      { bx = blockIdx.x; by = blockIdx.y; bz = blockIdx.z; }

    A += (size_t)bz * strideA;
    B += (size_t)bz * strideB;
    if (bias) bias += (size_t)bz * strideBias;

    const int tid  = threadIdx.x;
    const int lane = tid & 63;
    const int wv   = tid >> 6;
    const int wm   = wv >> 1;
    const int wn   = wv & 1;

    f32x4 acc[4][4] = {};

    // staging with XOR-swizzled source chunk: lane L -> LDS slot L (hw),
    // global chunk (L&3)^((L>>3)&3) of row L>>2. Reader uses chunk lq^((row>>1)&3).
    const int stgRow = lane >> 2;
    const int stgCh  = (lane & 3) ^ ((lane >> 3) & 3);
    const bf16* gA = A + (size_t)(by * 128 + wv * 32 + stgRow) * K + stgCh * 8;
    const bf16* gB = B + (size_t)(bx * 128 + wv * 32 + stgRow) * K + stgCh * 8;
    bf16* lA = &tA[(wv * 32) * 32];
    bf16* lB = &tB[(wv * 32) * 32];

    const int lr  = lane & 15;
    const int lq  = lane >> 4;
    const int rsw = (lr >> 1) & 3;       // row-swizzle bits (rows mod 16 = lr)
    const int chA = (lq ^ rsw) << 3;     // element offset of swizzled 16B chunk

    for (int k0 = 0; k0 < K; k0 += 32) {
        async16(gA,                  lA);
        async16(gA + (size_t)16 * K, lA + 16 * 32);
        async16(gB,                  lB);
        async16(gB + (size_t)16 * K, lB + 16 * 32);
        gA += 32; gB += 32;
        __syncthreads();

        bf16x8 af[4], bfr[4];
        #pragma unroll
        for (int i = 0; i < 4; ++i) {
            af[i]  = *(const bf16x8*)&tA[(wm * 64 + i * 16 + lr) * 32 + chA];
            bfr[i] = *(const bf16x8*)&tB[(wn * 64 + i * 16 + lr) * 32 + chA];
        }
        #pragma unroll
        for (int i = 0; i < 4; ++i)
            #pragma unroll
            for (int j = 0; j < 4; ++j)
                acc[i][j] = __builtin_amdgcn_mfma_f32_16x16x32_bf16(
                    af[i], bfr[j], acc[i][j], 0, 0, 0);
        __syncthreads();
    }

    // C/D layout: col = lane&15, row = (lane>>4)*4 + reg  [m89/m91]
    #pragma unroll
    for (int i = 0; i < 4; ++i) {
        #pragma unroll
        for (int j = 0; j < 4; ++j) {
            f32x4 v = acc[i][j];
            const int cg = bx * 128 + wn * 64 + j * 16 + lr;
            if (cg >= colBound) continue;
            const int rowBase = by * 128 + wm * 64 + i * 16 + lq * 4;
            const float bs = bias ? bias[cg] : 0.0f;
            #pragma unroll
            for (int r = 0; r < 4; ++r) {
                const int mg = rowBase + r;
                const float val = v[r];
                if (EPI == 0) {
                    ((bf16*)Out + (size_t)bz * strideOut)[(size_t)mg * outPitch + cg] =
                        (bf16)(val + bs);
                } else if (EPI == 3) {
                    const float u = val + bs;
                    const float g = 0.5f * u * (1.0f + erff(u * 0.70710678118654752f));
                    ((bf16*)Out)[(size_t)mg * outPitch + cg] = (bf16)g;
                } else if (EPI == 4) {
                    ((float*)Out)[(size_t)mg * outPitch + cg] =
                        val + bs + resid[(size_t)mg * outPitch + cg];
                } else if (EPI == 5) {
                    const int grp = cg / D_PADN;          // 0=Q,1=K,2=V
                    const int c   = cg - grp * D_PADN;
                    const float u = val + bs;
                    if (grp < 2) {
                        if (c < D_PADK)
                            ((bf16*)Out)[(size_t)bz * 2 * SLAB_X + (size_t)grp * SLAB_X +
                                         (size_t)mg * D_PADK + c] = (bf16)u;
                    } else {
                        OutV[(size_t)bz * VSLAB + (size_t)c * NTOK + mg] = (bf16)u;
                    }
                } else { // EPI == 6
                    ((bf16*)Out + (size_t)bz * strideOut)[(size_t)mg * outPitch + cg] =
                        (bf16)(val * scale);
                }
            }
        }
    }
}

// fp32 [R,C] -> zero-padded bf16 [gridDim.y, CP]
__global__ __launch_bounds__(256)
void cvt_pad(const float* __restrict__ src, int R, int C,
             bf16* __restrict__ dst, int CP)
{
    const int c = blockIdx.x * 256 + threadIdx.x;
    const int r = blockIdx.y;
    if (c >= CP) return;
    const float v = (r < R && c < C) ? src[(size_t)r * C + c] : 0.0f;
    dst[(size_t)r * CP + c] = (bf16)v;
}

__global__ __launch_bounds__(256)
void pad_bias(const float* __restrict__ src, int n, float* __restrict__ dst, int np)
{
    const int i = blockIdx.x * 256 + threadIdx.x;
    if (i < np) dst[i] = (i < n) ? src[i] : 0.0f;
}

// in-place row softmax over 2048 bf16 logits; one wave per row
__global__ __launch_bounds__(256)
void softmax_ip(bf16* __restrict__ S)
{
    const int row  = blockIdx.x * 4 + (threadIdx.x >> 6);
    const int lane = threadIdx.x & 63;
    bf16* s = S + (size_t)row * NTOK + lane * 8;

    float v[32];
    #pragma unroll
    for (int j = 0; j < 4; ++j) {
        bf16x8 t = *(const bf16x8*)(s + j * 512);
        #pragma unroll
        for (int e = 0; e < 8; ++e) v[j * 8 + e] = (float)t[e];
    }
    float m = -1e30f;
    #pragma unroll
    for (int i = 0; i < 32; ++i) m = fmaxf(m, v[i]);
    #pragma unroll
    for (int off = 32; off > 0; off >>= 1) m = fmaxf(m, __shfl_xor(m, off, 64));

    float sum = 0.0f;
    #pragma unroll
    for (int i = 0; i < 32; ++i) { v[i] = __expf(v[i] - m); sum += v[i]; }
    #pragma unroll
    for (int off = 32; off > 0; off >>= 1) sum += __shfl_xor(sum, off, 64);
    const float inv = 1.0f / sum;

    #pragma unroll
    for (int j = 0; j < 4; ++j) {
        bf16x8 t;
        #pragma unroll
        for (int e = 0; e < 8; ++e) t[e] = (bf16)(v[j * 8 + e] * inv);
        *(bf16x8*)(s + j * 512) = t;
    }
}

// ---------------------------------------------------------------------------
// fixed workspace (bytes): WQKV(3456x1056 bf16) 0..7,299,072  WE ..16,220,160
// WO ..25,952,256  BQKV(3456 f32) ..25,966,080  BE ..25,982,976
// XBF(16384x1056 bf16; attn overwrites in place) ..60,585,984
// VT(8x1152x2048 bf16) ..98,334,720 = OFF_SCR.  Scratch adaptive.
// ---------------------------------------------------------------------------
#define OFF_WQKV   0u
#define OFF_WE     7299072u
#define OFF_WO     16220160u
#define OFF_BQKV   25952256u
#define OFF_BE     25966080u
#define OFF_XBF    25982976u
#define OFF_VT     60585984u
#define OFF_SCR    98334720u
#define QS_BYTES   8650752u     // per-batch Q+K slabs
#define SS_BYTES   8388608u     // per-batch bf16 score slab

extern "C" void kernel_launch(void* const* d_in, const int* in_sizes, int n_in,
                              void* d_out, int out_size, void* d_ws, size_t ws_size,
                              hipStream_t stream)
{
    const float* x  = (const float*)d_in[0];
    const float* Wq = (const float*)d_in[1];
    const float* bq = (const float*)d_in[2];
    const float* Wk = (const float*)d_in[3];
    const float* bk = (const float*)d_in[4];
    const float* Wv = (const float*)d_in[5];
    const float* bv = (const float*)d_in[6];
    const float* We = (const float*)d_in[7];
    const float* be = (const float*)d_in[8];
    const float* Wo = (const float*)d_in[9];
    const float* bo = (const float*)d_in[10];

    char* ws = (char*)d_ws;
    bf16*  Wqkv = (bf16*)(ws + OFF_WQKV);
    bf16*  WeP  = (bf16*)(ws + OFF_WE);
    bf16*  WoP  = (bf16*)(ws + OFF_WO);
    float* Bqkv = (float*)(ws + OFF_BQKV);
    float* BeP  = (float*)(ws + OFF_BE);
    bf16*  Xbf  = (bf16*)(ws + OFF_XBF);
    bf16*  Vt   = (bf16*)(ws + OFF_VT);
    char*  scr  = ws + OFF_SCR;

    const size_t avail = ws_size > OFF_SCR ? ws_size - OFF_SCR : 0;
    const size_t perG  = (size_t)QS_BYTES + SS_BYTES;   // 17,039,360
    int G = (avail >= 8 * perG) ? 8 : (avail >= 4 * perG) ? 4
          : (avail >= 2 * perG) ? 2 : 1;
    int R = (avail >= 138412032u) ? 16384 : (avail >= 69206016u) ? 8192
          : (avail >= 34603008u) ? 4096 : 2048;

    bf16* Qs = (bf16*)scr;                                // [G][2] Q,K slabs
    bf16* Ss = (bf16*)(scr + (size_t)G * QS_BYTES);       // [G] score slabs
    bf16* Hb = (bf16*)scr;                                // FFN phase alias

    const dim3 blk(256);
    const float inv_sqrt_d = (float)(1.0 / sqrt((double)D_REAL));

    // ---- convert + pad to bf16 ----
    cvt_pad<<<dim3(5, MTOT), blk, 0, stream>>>(x, MTOT, D_REAL, Xbf, D_PADK);
    cvt_pad<<<dim3(5, D_PADN), blk, 0, stream>>>(Wq, D_REAL, D_REAL, Wqkv, D_PADK);
    cvt_pad<<<dim3(5, D_PADN), blk, 0, stream>>>(Wk, D_REAL, D_REAL, Wqkv + WSLAB, D_PADK);
    cvt_pad<<<dim3(5, D_PADN), blk, 0, stream>>>(Wv, D_REAL, D_REAL, Wqkv + 2 * WSLAB, D_PADK);
    cvt_pad<<<dim3(5, H_PAD), blk, 0, stream>>>(We, H_REAL, D_REAL, WeP, D_PADK);
    cvt_pad<<<dim3(17, D_PADN), blk, 0, stream>>>(Wo, D_REAL, H_REAL, WoP, H_PAD);
    pad_bias<<<dim3(5), blk, 0, stream>>>(bq, D_REAL, Bqkv, D_PADN);
    pad_bias<<<dim3(5), blk, 0, stream>>>(bk, D_REAL, Bqkv + D_PADN, D_PADN);
    pad_bias<<<dim3(5), blk, 0, stream>>>(bv, D_REAL, Bqkv + 2 * D_PADN, D_PADN);
    pad_bias<<<dim3(17), blk, 0, stream>>>(be, H_REAL, BeP, H_PAD);

    // ---- attention, G batches per iteration ----
    for (int g0 = 0; g0 < NB; g0 += G) {
        // fused QKV projection: cols [0,1152)=Q, [1152,2304)=K, [2304,3456)=V^T
        gemm_bt<5, false><<<dim3(27, 16, G), blk, 0, stream>>>(
            Xbf + (size_t)g0 * SLAB_X, SLAB_X, Wqkv, 0, Bqkv, 0,
            Qs, 0, Vt + (size_t)g0 * VSLAB,
            D_PADK, 0, 3456, 1.0f, nullptr);
        // scores (bf16, scaled): XCD-pinned, batch fastest
        gemm_bt<6, true><<<dim3(G, 16, 16), blk, 0, stream>>>(
            Qs, 2 * SLAB_X, Qs + SLAB_X, 2 * SLAB_X, nullptr, 0,
            Ss, SLAB_S, nullptr, D_PADK, NTOK, NTOK, inv_sqrt_d, nullptr);
        // in-place softmax
        softmax_ip<<<dim3(G * 512), blk, 0, stream>>>(Ss);
        // attn = W @ Vt^T -> overwrite Xbf slab; XCD-pinned
        gemm_bt<0, true><<<dim3(G, 16, 9), blk, 0, stream>>>(
            Ss, SLAB_S, Vt + (size_t)g0 * VSLAB, VSLAB, nullptr, 0,
            Xbf + (size_t)g0 * SLAB_X, SLAB_X, nullptr,
            NTOK, D_PADK, D_PADK, 1.0f, nullptr);
    }

    // ---- FFN in R-row chunks ----
    for (int r0 = 0; r0 < MTOT; r0 += R) {
        gemm_bt<3, false><<<dim3(33, R / 128, 1), blk, 0, stream>>>(
            Xbf + (size_t)r0 * D_PADK, 0, WeP, 0, BeP, 0,
            Hb, 0, nullptr, D_PADK, H_PAD, H_PAD, 1.0f, nullptr);
        gemm_bt<4, false><<<dim3(9, R / 128, 1), blk, 0, stream>>>(
            Hb, 0, WoP, 0, bo, 0,
            (float*)d_out + (size_t)r0 * D_REAL, 0, nullptr,
            H_PAD, D_REAL, D_REAL, 1.0f, x + (size_t)r0 * D_REAL);
    }
}

// Round 4
// 1071.238 us; speedup vs baseline: 1.3117x; 1.1211x over previous
//
#include <hip/hip_runtime.h>
#include <hip/hip_bf16.h>
#include <cstdint>
#include <cmath>

// ---------------------------------------------------------------------------
// TransLayer block: fused QKV proj -> softmax(QK^T/sqrt(D)) V -> GELU FFN.
// B=8, N=2048, D=1028 (K-pad 1088 = 17*64, N-pad 1152), H=4112 (pad 4224).
// GEMMs: C = A @ B^T, K-contiguous bf16, fp32 acc, 128x128 tiles, BK=64,
// MFMA 16x16x32. LDS XOR-swizzled 8-chunk (conflict-free, verified R3: 0).
// FFN runs in 8192-row chunks so Hb (69 MB) stays L3-resident for FFN2.
// ---------------------------------------------------------------------------

typedef __bf16 bf16;
typedef __bf16 bf16x8 __attribute__((ext_vector_type(8)));
typedef float  f32x4  __attribute__((ext_vector_type(4)));

#define D_REAL   1028
#define D_PADK   1088   // K-dim pad (mult of 64)
#define D_PADN   1152
#define H_REAL   4112
#define H_PAD    4224   // 66*64
#define NTOK     2048
#define NB       8
#define MTOT     (NB*NTOK)               // 16384
#define SLAB_X   ((size_t)NTOK*D_PADK)   // 2,228,224 elems
#define SLAB_S   ((size_t)NTOK*NTOK)
#define WSLAB    ((size_t)D_PADN*D_PADK) // 1,253,376 elems
#define VSLAB    ((size_t)D_PADN*NTOK)

__device__ __forceinline__ void async16(const void* g, void* l) {
    __builtin_amdgcn_global_load_lds(
        (__attribute__((address_space(1))) void*)(uintptr_t)g,
        (__attribute__((address_space(3))) void*)(uint32_t)(uintptr_t)l,
        16, 0, 0);
}

// EPI: 0 = bf16 out (+bias), 3 = gelu(acc+bias)->bf16, 4 = fp32 acc+bias+resid,
//      5 = fused QKV (Q/K to slabs, V transposed to OutV), 6 = bf16 out*scale
template <int EPI, bool XPIN>
__global__ __launch_bounds__(256)
void gemm_bt(const bf16* __restrict__ A, size_t strideA,
             const bf16* __restrict__ B, size_t strideB,
             const float* __restrict__ bias, size_t strideBias,
             void* __restrict__ Out, size_t strideOut,
             bf16* __restrict__ OutV,
             int K, int outPitch, int colBound, float scale,
             const float* __restrict__ resid)
{
    __shared__ __attribute__((aligned(16))) bf16 tA[128 * 64];  // 16 KB
    __shared__ __attribute__((aligned(16))) bf16 tB[128 * 64];  // 16 KB

    int bx, by, bz;
    if (XPIN) { bz = blockIdx.x; by = blockIdx.y; bx = blockIdx.z; }
    else      { bx = blockIdx.x; by = blockIdx.y; bz = blockIdx.z; }

    A += (size_t)bz * strideA;
    B += (size_t)bz * strideB;
    if (bias) bias += (size_t)bz * strideBias;

    const int tid  = threadIdx.x;
    const int lane = tid & 63;
    const int wv   = tid >> 6;
    const int wm   = wv >> 1;
    const int wn   = wv & 1;

    f32x4 acc[4][4] = {};

    // staging: wave wv covers rows [wv*32, wv*32+32) of each 128x64 tile.
    // Each async16 covers 8 rows (64 lanes x 16B). Lane L -> row L>>3,
    // LDS slot L&7, sourcing global chunk (L&7)^((L>>3)&7) of that row, so
    // LDS(row, slot) = global(row, slot^(row&7)).
    const int sRow = lane >> 3;
    const int sCh  = (lane & 7) ^ sRow;
    const bf16* gA = A + (size_t)(by * 128 + wv * 32 + sRow) * K + sCh * 8;
    const bf16* gB = B + (size_t)(bx * 128 + wv * 32 + sRow) * K + sCh * 8;
    bf16* lA = &tA[(wv * 32) * 64];
    bf16* lB = &tB[(wv * 32) * 64];

    const int lr  = lane & 15;
    const int lq  = lane >> 4;
    const int rsw = lr & 7;              // row swizzle bits

    for (int k0 = 0; k0 < K; k0 += 64) {
        async16(gA,                  lA);
        async16(gA + (size_t) 8 * K, lA +  8 * 64);
        async16(gA + (size_t)16 * K, lA + 16 * 64);
        async16(gA + (size_t)24 * K, lA + 24 * 64);
        async16(gB,                  lB);
        async16(gB + (size_t) 8 * K, lB +  8 * 64);
        async16(gB + (size_t)16 * K, lB + 16 * 64);
        async16(gB + (size_t)24 * K, lB + 24 * 64);
        gA += 64; gB += 64;
        __syncthreads();

        #pragma unroll
        for (int kk = 0; kk < 2; ++kk) {
            const int sl = ((kk * 4 + lq) ^ rsw) << 3;   // element offset
            bf16x8 af[4], bfr[4];
            #pragma unroll
            for (int i = 0; i < 4; ++i) {
                af[i]  = *(const bf16x8*)&tA[(wm * 64 + i * 16 + lr) * 64 + sl];
                bfr[i] = *(const bf16x8*)&tB[(wn * 64 + i * 16 + lr) * 64 + sl];
            }
            #pragma unroll
            for (int i = 0; i < 4; ++i)
                #pragma unroll
                for (int j = 0; j < 4; ++j)
                    acc[i][j] = __builtin_amdgcn_mfma_f32_16x16x32_bf16(
                        af[i], bfr[j], acc[i][j], 0, 0, 0);
        }
        __syncthreads();
    }

    // C/D layout: col = lane&15, row = (lane>>4)*4 + reg  [m89/m91]
    #pragma unroll
    for (int i = 0; i < 4; ++i) {
        #pragma unroll
        for (int j = 0; j < 4; ++j) {
            f32x4 v = acc[i][j];
            const int cg = bx * 128 + wn * 64 + j * 16 + lr;
            if (cg >= colBound) continue;
            const int rowBase = by * 128 + wm * 64 + i * 16 + lq * 4;
            const float bs = bias ? bias[cg] : 0.0f;
            #pragma unroll
            for (int r = 0; r < 4; ++r) {
                const int mg = rowBase + r;
                const float val = v[r];
                if (EPI == 0) {
                    ((bf16*)Out + (size_t)bz * strideOut)[(size_t)mg * outPitch + cg] =
                        (bf16)(val + bs);
                } else if (EPI == 3) {
                    const float u = val + bs;
                    const float g = 0.5f * u * (1.0f + erff(u * 0.70710678118654752f));
                    ((bf16*)Out)[(size_t)mg * outPitch + cg] = (bf16)g;
                } else if (EPI == 4) {
                    ((float*)Out)[(size_t)mg * outPitch + cg] =
                        val + bs + resid[(size_t)mg * outPitch + cg];
                } else if (EPI == 5) {
                    const int grp = cg / D_PADN;          // 0=Q,1=K,2=V
                    const int c   = cg - grp * D_PADN;
                    const float u = val + bs;
                    if (grp < 2) {
                        if (c < D_PADK)
                            ((bf16*)Out)[(size_t)bz * 2 * SLAB_X + (size_t)grp * SLAB_X +
                                         (size_t)mg * D_PADK + c] = (bf16)u;
                    } else {
                        OutV[(size_t)bz * VSLAB + (size_t)c * NTOK + mg] = (bf16)u;
                    }
                } else { // EPI == 6
                    ((bf16*)Out + (size_t)bz * strideOut)[(size_t)mg * outPitch + cg] =
                        (bf16)(val * scale);
                }
            }
        }
    }
}

// fp32 [R,C] -> zero-padded bf16 [gridDim.y, CP]
__global__ __launch_bounds__(256)
void cvt_pad(const float* __restrict__ src, int R, int C,
             bf16* __restrict__ dst, int CP)
{
    const int c = blockIdx.x * 256 + threadIdx.x;
    const int r = blockIdx.y;
    if (c >= CP) return;
    const float v = (r < R && c < C) ? src[(size_t)r * C + c] : 0.0f;
    dst[(size_t)r * CP + c] = (bf16)v;
}

__global__ __launch_bounds__(256)
void pad_bias(const float* __restrict__ src, int n, float* __restrict__ dst, int np)
{
    const int i = blockIdx.x * 256 + threadIdx.x;
    if (i < np) dst[i] = (i < n) ? src[i] : 0.0f;
}

// in-place row softmax over 2048 bf16 logits; one wave per row
__global__ __launch_bounds__(256)
void softmax_ip(bf16* __restrict__ S)
{
    const int row  = blockIdx.x * 4 + (threadIdx.x >> 6);
    const int lane = threadIdx.x & 63;
    bf16* s = S + (size_t)row * NTOK + lane * 8;

    float v[32];
    #pragma unroll
    for (int j = 0; j < 4; ++j) {
        bf16x8 t = *(const bf16x8*)(s + j * 512);
        #pragma unroll
        for (int e = 0; e < 8; ++e) v[j * 8 + e] = (float)t[e];
    }
    float m = -1e30f;
    #pragma unroll
    for (int i = 0; i < 32; ++i) m = fmaxf(m, v[i]);
    #pragma unroll
    for (int off = 32; off > 0; off >>= 1) m = fmaxf(m, __shfl_xor(m, off, 64));

    float sum = 0.0f;
    #pragma unroll
    for (int i = 0; i < 32; ++i) { v[i] = __expf(v[i] - m); sum += v[i]; }
    #pragma unroll
    for (int off = 32; off > 0; off >>= 1) sum += __shfl_xor(sum, off, 64);
    const float inv = 1.0f / sum;

    #pragma unroll
    for (int j = 0; j < 4; ++j) {
        bf16x8 t;
        #pragma unroll
        for (int e = 0; e < 8; ++e) t[e] = (bf16)(v[j * 8 + e] * inv);
        *(bf16x8*)(s + j * 512) = t;
    }
}

// ---------------------------------------------------------------------------
// fixed workspace (bytes):
//   WQKV(3*1152x1088 bf16) 0..7,520,256   WE(4224x1088) ..16,711,680
//   WO(1152x4224) ..26,443,776  BQKV ..26,457,600  BE ..26,474,496
//   XBF(16384x1088; attn overwrites in place) ..62,126,080
//   VT(8x1152x2048) ..99,874,816 = OFF_SCR.  Scratch adaptive.
// ---------------------------------------------------------------------------
#define OFF_WQKV   0u
#define OFF_WE     7520256u
#define OFF_WO     16711680u
#define OFF_BQKV   26443776u
#define OFF_BE     26457600u
#define OFF_XBF    26474496u
#define OFF_VT     62126080u
#define OFF_SCR    99874816u
#define QS_BYTES   8912896u     // per-batch Q+K slabs (2 * 2048*1088 * 2B)
#define SS_BYTES   8388608u     // per-batch bf16 score slab

extern "C" void kernel_launch(void* const* d_in, const int* in_sizes, int n_in,
                              void* d_out, int out_size, void* d_ws, size_t ws_size,
                              hipStream_t stream)
{
    const float* x  = (const float*)d_in[0];
    const float* Wq = (const float*)d_in[1];
    const float* bq = (const float*)d_in[2];
    const float* Wk = (const float*)d_in[3];
    const float* bk = (const float*)d_in[4];
    const float* Wv = (const float*)d_in[5];
    const float* bv = (const float*)d_in[6];
    const float* We = (const float*)d_in[7];
    const float* be = (const float*)d_in[8];
    const float* Wo = (const float*)d_in[9];
    const float* bo = (const float*)d_in[10];

    char* ws = (char*)d_ws;
    bf16*  Wqkv = (bf16*)(ws + OFF_WQKV);
    bf16*  WeP  = (bf16*)(ws + OFF_WE);
    bf16*  WoP  = (bf16*)(ws + OFF_WO);
    float* Bqkv = (float*)(ws + OFF_BQKV);
    float* BeP  = (float*)(ws + OFF_BE);
    bf16*  Xbf  = (bf16*)(ws + OFF_XBF);
    bf16*  Vt   = (bf16*)(ws + OFF_VT);
    char*  scr  = ws + OFF_SCR;

    const size_t avail = ws_size > OFF_SCR ? ws_size - OFF_SCR : 0;
    const size_t perG  = (size_t)QS_BYTES + SS_BYTES;   // 17,301,504
    int G = (avail >= 8 * perG) ? 8 : (avail >= 4 * perG) ? 4
          : (avail >= 2 * perG) ? 2 : 1;
    // FFN chunk rows: keep Hb (R*4224*2 B) L3-resident; 8192 -> 69 MB.
    int R = (avail >= 69206016u) ? 8192 : (avail >= 34603008u) ? 4096 : 2048;

    bf16* Qs = (bf16*)scr;                                // [G][2] Q,K slabs
    bf16* Ss = (bf16*)(scr + (size_t)G * QS_BYTES);       // [G] score slabs
    bf16* Hb = (bf16*)scr;                                // FFN phase alias

    const dim3 blk(256);
    const float inv_sqrt_d = (float)(1.0 / sqrt((double)D_REAL));

    // ---- convert + pad to bf16 ----
    cvt_pad<<<dim3(5, MTOT), blk, 0, stream>>>(x, MTOT, D_REAL, Xbf, D_PADK);
    cvt_pad<<<dim3(5, D_PADN), blk, 0, stream>>>(Wq, D_REAL, D_REAL, Wqkv, D_PADK);
    cvt_pad<<<dim3(5, D_PADN), blk, 0, stream>>>(Wk, D_REAL, D_REAL, Wqkv + WSLAB, D_PADK);
    cvt_pad<<<dim3(5, D_PADN), blk, 0, stream>>>(Wv, D_REAL, D_REAL, Wqkv + 2 * WSLAB, D_PADK);
    cvt_pad<<<dim3(5, H_PAD), blk, 0, stream>>>(We, H_REAL, D_REAL, WeP, D_PADK);
    cvt_pad<<<dim3(17, D_PADN), blk, 0, stream>>>(Wo, D_REAL, H_REAL, WoP, H_PAD);
    pad_bias<<<dim3(5), blk, 0, stream>>>(bq, D_REAL, Bqkv, D_PADN);
    pad_bias<<<dim3(5), blk, 0, stream>>>(bk, D_REAL, Bqkv + D_PADN, D_PADN);
    pad_bias<<<dim3(5), blk, 0, stream>>>(bv, D_REAL, Bqkv + 2 * D_PADN, D_PADN);
    pad_bias<<<dim3(17), blk, 0, stream>>>(be, H_REAL, BeP, H_PAD);

    // ---- attention, G batches per iteration ----
    for (int g0 = 0; g0 < NB; g0 += G) {
        // fused QKV projection: cols [0,1152)=Q, [1152,2304)=K, [2304,3456)=V^T
        gemm_bt<5, false><<<dim3(27, 16, G), blk, 0, stream>>>(
            Xbf + (size_t)g0 * SLAB_X, SLAB_X, Wqkv, 0, Bqkv, 0,
            Qs, 0, Vt + (size_t)g0 * VSLAB,
            D_PADK, 0, 3456, 1.0f, nullptr);
        // scores (bf16, scaled): XCD-pinned, batch fastest
        gemm_bt<6, true><<<dim3(G, 16, 16), blk, 0, stream>>>(
            Qs, 2 * SLAB_X, Qs + SLAB_X, 2 * SLAB_X, nullptr, 0,
            Ss, SLAB_S, nullptr, D_PADK, NTOK, NTOK, inv_sqrt_d, nullptr);
        // in-place softmax
        softmax_ip<<<dim3(G * 512), blk, 0, stream>>>(Ss);
        // attn = W @ Vt^T -> overwrite Xbf slab; XCD-pinned
        gemm_bt<0, true><<<dim3(G, 16, 9), blk, 0, stream>>>(
            Ss, SLAB_S, Vt + (size_t)g0 * VSLAB, VSLAB, nullptr, 0,
            Xbf + (size_t)g0 * SLAB_X, SLAB_X, nullptr,
            NTOK, D_PADK, D_PADK, 1.0f, nullptr);
    }

    // ---- FFN in R-row chunks (Hb stays L3-resident) ----
    for (int r0 = 0; r0 < MTOT; r0 += R) {
        gemm_bt<3, false><<<dim3(33, R / 128, 1), blk, 0, stream>>>(
            Xbf + (size_t)r0 * D_PADK, 0, WeP, 0, BeP, 0,
            Hb, 0, nullptr, D_PADK, H_PAD, H_PAD, 1.0f, nullptr);
        gemm_bt<4, false><<<dim3(9, R / 128, 1), blk, 0, stream>>>(
            Hb, 0, WoP, 0, bo, 0,
            (float*)d_out + (size_t)r0 * D_REAL, 0, nullptr,
            H_PAD, D_REAL, D_REAL, 1.0f, x + (size_t)r0 * D_REAL);
    }
}